// Round 6
// baseline (186.472 us; speedup 1.0000x reference)
//
#include <hip/hip_runtime.h>
#include <hip/hip_bf16.h>

#define B_TOT 65536
#define S 9
#define D 20
#define DFF 512
#define EPS 1e-5f

typedef short bf16x8 __attribute__((ext_vector_type(8)));
typedef float f32x4 __attribute__((ext_vector_type(4)));

// ws layout (short index unless noted):
//   PQKV  [4ct][64][8] bf16 @ short 0     : B-frags of [Wq|Wk|Wv] (d 20pad32, j 60pad64)
//   PWO   [2ct][64][8] bf16 @ short 2048  : B-frags of Wo (d 20pad32, j 20pad32)
//   BQKV  f32[64]          @ float 1536   : concat bq|bk|bv (pad 0)
//   PA1   [32frag][64][8]  @ short 3200   : W1 A-frags, PERMUTED (round-5 layout, unchanged)
//   PB2   [32frag][64][8]  @ short 19584  : W2 B-frags (round-5 layout, unchanged)
#define SH_PQKV 0
#define SH_PWO 2048
#define FL_BQKV 1536
#define SH_PA1 3200
#define SH_PB2 19584

#define N_PQKV 2048
#define N_PWO 1024
#define N_B 64
#define N_PA1 16384
#define N_PB2 16384
#define PREP_TOTAL (N_PQKV + N_PWO + N_B + N_PA1 + N_PB2)

__device__ __forceinline__ unsigned short f2bf(float f) {
  union { __hip_bfloat16 h; unsigned short u; } v;
  v.h = __float2bfloat16(f);
  return v.u;
}
__device__ __forceinline__ float bf2f(unsigned short h) {
  union { unsigned u; float f; } v; v.u = ((unsigned)h) << 16; return v.f;
}
__device__ __forceinline__ unsigned cvt2(float a, float b) {
  union { __hip_bfloat162 h; unsigned u; } v;
  v.h = __float22bfloat162_rn(make_float2(a, b));
  return v.u;
}
__device__ __forceinline__ void unpk(unsigned u, float& lo, float& hi) {
  union { unsigned v; float f; } a, b;
  a.v = u << 16; b.v = u & 0xffff0000u;
  lo = a.f; hi = b.f;
}
__device__ __forceinline__ void unpack20(uint4 a, uint4 b, uint2 c, float* o) {
  unpk(a.x, o[0], o[1]); unpk(a.y, o[2], o[3]); unpk(a.z, o[4], o[5]); unpk(a.w, o[6], o[7]);
  unpk(b.x, o[8], o[9]); unpk(b.y, o[10], o[11]); unpk(b.z, o[12], o[13]); unpk(b.w, o[14], o[15]);
  unpk(c.x, o[16], o[17]); unpk(c.y, o[18], o[19]);
}

__global__ void prep_kernel(const float* __restrict__ Wq, const float* __restrict__ Wk,
                            const float* __restrict__ Wv, const float* __restrict__ Wo,
                            const float* __restrict__ W1, const float* __restrict__ W2,
                            const float* __restrict__ bq, const float* __restrict__ bk,
                            const float* __restrict__ bv, float* __restrict__ wsf) {
  int stride = gridDim.x * blockDim.x;
  unsigned short* P = (unsigned short*)wsf;
  for (int i = blockIdx.x * blockDim.x + threadIdx.x; i < PREP_TOTAL; i += stride) {
    if (i < N_PQKV) {
      // PQKV: B[k=d][col=j] for concat [Wq|Wk|Wv]
      int ct = i >> 9, rem = i & 511, l = rem >> 3, jj = rem & 7;
      int d = 8 * (l >> 4) + jj, j = ct * 16 + (l & 15);
      unsigned short v = 0;
      if (d < 20 && j < 60) {
        int mat = j / 20, jc = j % 20;
        const float* Wsrc = (mat == 0) ? Wq : (mat == 1) ? Wk : Wv;
        v = f2bf(Wsrc[d * 20 + jc]);
      }
      P[SH_PQKV + i] = v;
    } else if (i < N_PQKV + N_PWO) {
      int p = i - N_PQKV;
      int ct = p >> 9, rem = p & 511, l = rem >> 3, jj = rem & 7;
      int d = 8 * (l >> 4) + jj, j = ct * 16 + (l & 15);
      P[SH_PWO + p] = (d < 20 && j < 20) ? f2bf(Wo[d * 20 + j]) : (unsigned short)0;
    } else if (i < N_PQKV + N_PWO + N_B) {
      int j = i - (N_PQKV + N_PWO);
      float v = 0.f;
      if (j < 20) v = bq[j];
      else if (j < 40) v = bk[j - 20];
      else if (j < 60) v = bv[j - 40];
      wsf[FL_BQKV + j] = v;
    } else if (i < N_PQKV + N_PWO + N_B + N_PA1) {
      // PA1: permuted W1 A-fragments (unchanged from round 5)
      int j = i - (N_PQKV + N_PWO + N_B);
      int frag = j >> 9, rem = j & 511;
      int l = rem >> 3, jj = rem & 7;
      int p = frag & 1, q2 = (frag >> 1) & 3, ch = frag >> 3;
      int g2 = l >> 4, cl2 = l & 15;
      int k = 8 * g2 + jj;
      int f = ch * 128 + q2 * 32 + 8 * (cl2 >> 2) + 4 * p + (cl2 & 3);
      P[SH_PA1 + j] = (k < 20) ? f2bf(W1[k * DFF + f]) : (unsigned short)0;
    } else {
      // PB2 (unchanged from round 5)
      int j = i - (N_PQKV + N_PWO + N_B + N_PA1);
      int pair = j >> 9, rem = j & 511;
      int l = rem >> 3, jj = rem & 7;
      int g = l >> 4, cl = l & 15;
      int kk = pair >> 1, cc = pair & 1;
      int kg = kk * 32 + 8 * g + jj;
      int d = cc * 16 + cl;
      P[SH_PB2 + j] = (d < 20) ? f2bf(W2[kg * 20 + d]) : (unsigned short)0;
    }
  }
}

// Per-wave LDS slab, 10240 B, all wave-private (NO __syncthreads).
// Region A (RA, 4096 B), sequential lifetimes:
//   Xstage bf16 [64][32] rows 64B  ->  q bf16 rows 48B  ->  ao bf16 rows 48B  ->  Y bf16 [64][32] rows 64B
// Region B (RB, 6144 B):
//   k/v bf16 rows 96B (k @ +0 20 elems, v @ +48 20 elems)  ->  merged bf16 [64][32] rows 64B
// Overlays are fenced (asm memory clobber + sched_barrier); all strides linear
// (round-4 lesson: staggered offsets without allocated pad overlap rows).
#define SLAB_BYTES 10240
#define RA 0
#define RB 4096

#define FENCE() do { asm volatile("" ::: "memory"); __builtin_amdgcn_sched_barrier(0); } while (0)

__global__ __launch_bounds__(256, 4) void encoder_kernel(
    const float* __restrict__ X, const float* __restrict__ ws,
    const float* __restrict__ bo, const float* __restrict__ g1,
    const float* __restrict__ b1, const float* __restrict__ g2,
    const float* __restrict__ b2, float* __restrict__ Out) {
  __shared__ __align__(16) char smem[4 * SLAB_BYTES];

  const unsigned short* P16 = (const unsigned short*)ws;
  const unsigned short* PQKV = P16 + SH_PQKV;
  const unsigned short* PWO = P16 + SH_PWO;
  const float* BQKV = ws + FL_BQKV;
  const unsigned short* PA1 = P16 + SH_PA1;
  const unsigned short* PB2 = P16 + SH_PB2;

  const int tid = threadIdx.x;
  const int wv = tid >> 6;
  const int lane = tid & 63;
  const int bl = lane / 9;     // 0..7 (7 == pad lane 63)
  const int s = lane - bl * 9;
  const long wb = (long)blockIdx.x * 4 + wv;
  const long bb = wb * 7 + bl;
  const bool active = (bl < 7) && (bb < B_TOT);

  char* slab = smem + wv * SLAB_BYTES;
  const int cl = lane & 15;
  const int g = lane >> 4;
  const f32x4 zero4 = {0.f, 0.f, 0.f, 0.f};

  // ---------------- stage X as bf16 rows (zeros for inactive rows) ----------
  {
    float x[20];
    if (active) {
      const float4* xr = (const float4*)(X + bb * (S * D) + s * D);
#pragma unroll
      for (int i = 0; i < 5; ++i) {
        float4 t = xr[i];
        x[4 * i + 0] = t.x; x[4 * i + 1] = t.y; x[4 * i + 2] = t.z; x[4 * i + 3] = t.w;
      }
    } else {
#pragma unroll
      for (int i = 0; i < 20; ++i) x[i] = 0.f;
    }
    unsigned u[10];
#pragma unroll
    for (int i = 0; i < 10; ++i) u[i] = cvt2(x[2 * i], x[2 * i + 1]);
    uint4* dst = (uint4*)(slab + RA + lane * 64);
    dst[0] = make_uint4(u[0], u[1], u[2], u[3]);
    dst[1] = make_uint4(u[4], u[5], u[6], u[7]);
    dst[2] = make_uint4(u[8], u[9], 0u, 0u);
    dst[3] = make_uint4(0u, 0u, 0u, 0u);
  }
  FENCE();

  // ---------------- X A-frags -----------------------------------------------
  bf16x8 xf[4];
#pragma unroll
  for (int rt = 0; rt < 4; ++rt)
    xf[rt] = *(const bf16x8*)(slab + RA + (rt * 16 + cl) * 64 + g * 16);
  FENCE();  // X reads before q-scatter overwrites region A

  // ---------------- QKV via MFMA (concat B), scatter bf16 rows --------------
#pragma unroll
  for (int ct = 0; ct < 4; ++ct) {
    bf16x8 wf = *(const bf16x8*)(PQKV + (size_t)(ct * 64 + lane) * 8);
    const int j = ct * 16 + cl;
    const float bias = BQKV[j];
    const int mat = (j * 3277) >> 16;   // j/20
    const int jc = j - 20 * mat;
    const bool valid = j < 60;
    const int off = (mat == 0) ? (RA + jc * 2) : (RB + ((mat == 2) ? 48 : 0) + jc * 2);
    const int rstride = (mat == 0) ? 48 : 96;
    f32x4 dm[4];
#pragma unroll
    for (int rt = 0; rt < 4; ++rt)
      dm[rt] = __builtin_amdgcn_mfma_f32_16x16x32_bf16(xf[rt], wf, zero4, 0, 0, 0);
    if (valid) {
#pragma unroll
      for (int rt = 0; rt < 4; ++rt)
#pragma unroll
        for (int r = 0; r < 4; ++r)
          *(unsigned short*)(slab + off + (rt * 16 + 4 * g + r) * rstride) =
              f2bf(dm[rt][r] + bias);
    }
  }
  FENCE();  // scatters before q/k/v row reads

  // ---------------- attention (per-lane-row, bf16 rows) ---------------------
  float sc[4][9];
  float inv4[4];
  float ctx[20];
  if (active) {
    float q[20];
    {
      const char* qp = slab + RA + lane * 48;
      uint4 a = *(const uint4*)qp;
      uint4 b = *(const uint4*)(qp + 16);
      uint4 c = *(const uint4*)(qp + 32);  // only .x,.y meaningful
      unpack20(a, b, make_uint2(c.x, c.y), q);
    }
#pragma unroll
    for (int t = 0; t < 9; ++t) {
      const char* kp = slab + RB + (bl * 9 + t) * 96;
      uint4 a = *(const uint4*)kp;
      uint4 b = *(const uint4*)(kp + 16);
      uint2 c = *(const uint2*)(kp + 32);
      float kt[20];
      unpack20(a, b, c, kt);
#pragma unroll
      for (int h = 0; h < 4; ++h) {
        float d0 = q[h * 5 + 0] * kt[h * 5 + 0] + q[h * 5 + 1] * kt[h * 5 + 1];
        float d1 = q[h * 5 + 2] * kt[h * 5 + 2] + q[h * 5 + 3] * kt[h * 5 + 3];
        sc[h][t] = d0 + d1 + q[h * 5 + 4] * kt[h * 5 + 4];
      }
    }
#pragma unroll
    for (int h = 0; h < 4; ++h) {
      float mx = sc[h][0];
#pragma unroll
      for (int t = 1; t < 9; ++t) mx = fmaxf(mx, sc[h][t]);
      float sum = 0.f;
#pragma unroll
      for (int t = 0; t < 9; ++t) {
        sc[h][t] = __expf((sc[h][t] - mx) * (1.0f / 3.0f));
        sum += sc[h][t];
      }
      inv4[h] = 1.0f / sum;
    }
#pragma unroll
    for (int j = 0; j < 20; ++j) ctx[j] = 0.f;
#pragma unroll
    for (int t = 0; t < 9; ++t) {
      const char* vp = slab + RB + (bl * 9 + t) * 96 + 48;
      uint4 a = *(const uint4*)vp;
      uint4 b = *(const uint4*)(vp + 16);
      uint2 c = *(const uint2*)(vp + 32);
      float vt[20];
      unpack20(a, b, c, vt);
#pragma unroll
      for (int h = 0; h < 4; ++h)
#pragma unroll
        for (int dh = 0; dh < 5; ++dh)
          ctx[h * 5 + dh] += sc[h][t] * vt[h * 5 + dh];
    }
#pragma unroll
    for (int h = 0; h < 4; ++h)
#pragma unroll
      for (int dh = 0; dh < 5; ++dh)
        ctx[h * 5 + dh] *= inv4[h];
  }
  FENCE();  // k/v reads before merged overlay writes

  // ---------------- merged-ctx scatter (transpose quirk) --------------------
  if (active) {
    int m = s;  // m = 9*w + s, w = 5h+dh
#pragma unroll
    for (int w = 0; w < 20; ++w) {
      int row = (m * 3277) >> 16;  // m/20
      int col = m - 20 * row;
      *(unsigned short*)(slab + RB + (bl * 9 + row) * 64 + col * 2) = f2bf(ctx[w]);
      m += 9;
    }
  }
  // zero-pad merged cols 20..31 (every lane owns its row)
  *(uint2*)(slab + RB + lane * 64 + 40) = make_uint2(0u, 0u);
  *(uint4*)(slab + RB + lane * 64 + 48) = make_uint4(0u, 0u, 0u, 0u);
  FENCE();  // merged writes before frag reads

  // ---------------- Wo via MFMA, scatter ao rows ----------------------------
  bf16x8 mf[4];
#pragma unroll
  for (int rt = 0; rt < 4; ++rt)
    mf[rt] = *(const bf16x8*)(slab + RB + (rt * 16 + cl) * 64 + g * 16);
  FENCE();
#pragma unroll
  for (int ct = 0; ct < 2; ++ct) {
    bf16x8 wof = *(const bf16x8*)(PWO + (size_t)(ct * 64 + lane) * 8);
    const int j = ct * 16 + cl;
    const bool jv = j < 20;
    float bov = 0.f;
    if (jv) bov = bo[j];
#pragma unroll
    for (int rt = 0; rt < 4; ++rt) {
      f32x4 d = __builtin_amdgcn_mfma_f32_16x16x32_bf16(mf[rt], wof, zero4, 0, 0, 0);
      if (jv) {
#pragma unroll
        for (int r = 0; r < 4; ++r)
          *(unsigned short*)(slab + RA + (rt * 16 + 4 * g + r) * 48 + j * 2) =
              f2bf(d[r] + bov);
      }
    }
  }
  FENCE();  // ao writes before ao row reads

  // ---------------- LN1 per-row (x reloaded fp32 for residual) --------------
  float y[20];
  if (active) {
    float x[20];
    const float4* xr = (const float4*)(X + bb * (S * D) + s * D);
#pragma unroll
    for (int i = 0; i < 5; ++i) {
      float4 t = xr[i];
      x[4 * i + 0] = t.x; x[4 * i + 1] = t.y; x[4 * i + 2] = t.z; x[4 * i + 3] = t.w;
    }
    const char* ap = slab + RA + lane * 48;
    uint4 a = *(const uint4*)ap;
    uint4 b = *(const uint4*)(ap + 16);
    uint2 c = *(const uint2*)(ap + 32);
    float ao[20];
    unpack20(a, b, c, ao);
    float z[20];
#pragma unroll
    for (int d = 0; d < 20; ++d) z[d] = ao[d] + x[d];
    float t0 = 0.f;
#pragma unroll
    for (int d = 0; d < 20; ++d) t0 += z[d];
    float mean = t0 * (1.0f / 20.0f);
    float var = 0.f;
#pragma unroll
    for (int d = 0; d < 20; ++d) { z[d] -= mean; var += z[d] * z[d]; }
    float rs = rsqrtf(var * (1.0f / 20.0f) + EPS);
#pragma unroll
    for (int d = 0; d < 20; ++d) y[d] = z[d] * rs * g1[d] + b1[d];
  } else {
#pragma unroll
    for (int d = 0; d < 20; ++d) y[d] = 0.f;
  }
  FENCE();  // ao reads before Y overlay writes

  // ---------------- stage Y bf16 rows ---------------------------------------
  {
    unsigned u[10];
#pragma unroll
    for (int i = 0; i < 10; ++i) u[i] = cvt2(y[2 * i], y[2 * i + 1]);
    uint4* dst = (uint4*)(slab + RA + lane * 64);
    dst[0] = make_uint4(u[0], u[1], u[2], u[3]);
    dst[1] = make_uint4(u[4], u[5], u[6], u[7]);
    dst[2] = make_uint4(u[8], u[9], 0u, 0u);
    dst[3] = make_uint4(0u, 0u, 0u, 0u);
  }
  FENCE();  // Y writes before cross-lane frag reads

  // ---------------- FFN via MFMA (register-resident H, round-5 flow) --------
  bf16x8 ytf[4];
#pragma unroll
  for (int rt = 0; rt < 4; ++rt)
    ytf[rt] = *(const bf16x8*)(slab + RA + (rt * 16 + cl) * 64 + g * 16);

  f32x4 acc[4][2];
#pragma unroll
  for (int rt = 0; rt < 4; ++rt) { acc[rt][0] = zero4; acc[rt][1] = zero4; }

  for (int ch = 0; ch < 4; ++ch) {
#pragma unroll
    for (int q2 = 0; q2 < 4; ++q2) {
      const int fb = ch * 8 + q2 * 2;
      bf16x8 aw0 = *(const bf16x8*)(PA1 + (size_t)(fb * 64 + lane) * 8);
      bf16x8 aw1 = *(const bf16x8*)(PA1 + (size_t)((fb + 1) * 64 + lane) * 8);
      bf16x8 bw0 = *(const bf16x8*)(PB2 + (size_t)(fb * 64 + lane) * 8);
      bf16x8 bw1 = *(const bf16x8*)(PB2 + (size_t)((fb + 1) * 64 + lane) * 8);
#pragma unroll
      for (int rt = 0; rt < 4; ++rt) {
        f32x4 d0 = __builtin_amdgcn_mfma_f32_16x16x32_bf16(aw0, ytf[rt], zero4, 0, 0, 0);
        f32x4 d1 = __builtin_amdgcn_mfma_f32_16x16x32_bf16(aw1, ytf[rt], zero4, 0, 0, 0);
        union { bf16x8 v; unsigned uu[4]; } af;
        af.uu[0] = cvt2(fmaxf(d0[0], 0.f), fmaxf(d0[1], 0.f));
        af.uu[1] = cvt2(fmaxf(d0[2], 0.f), fmaxf(d0[3], 0.f));
        af.uu[2] = cvt2(fmaxf(d1[0], 0.f), fmaxf(d1[1], 0.f));
        af.uu[3] = cvt2(fmaxf(d1[2], 0.f), fmaxf(d1[3], 0.f));
        acc[rt][0] = __builtin_amdgcn_mfma_f32_16x16x32_bf16(af.v, bw0, acc[rt][0], 0, 0, 0);
        acc[rt][1] = __builtin_amdgcn_mfma_f32_16x16x32_bf16(af.v, bw1, acc[rt][1], 0, 0, 0);
      }
    }
  }

  // ---------------- LN2 in fragment space + store ----------------------------
  const float gg0 = g2[cl], bb0 = b2[cl];
  const float gg1 = (cl < 4) ? g2[16 + cl] : 0.f;
  const float bb1 = (cl < 4) ? b2[16 + cl] : 0.f;
  const long wrbase = wb * 63;
  const long total_rows = (long)B_TOT * S;

#pragma unroll
  for (int rt = 0; rt < 4; ++rt) {
#pragma unroll
    for (int r = 0; r < 4; ++r) {
      const int rrow = rt * 16 + 4 * g + r;
      float y0 = bf2f(*(const unsigned short*)(slab + RA + rrow * 64 + cl * 2));
      float y1 = (cl < 4) ? bf2f(*(const unsigned short*)(slab + RA + rrow * 64 + 32 + cl * 2)) : 0.f;
      float z0 = acc[rt][0][r] + y0;
      float z1 = acc[rt][1][r] + y1;
      float t = z0 + ((cl < 4) ? z1 : 0.f);
      t += __shfl_xor(t, 1, 16);
      t += __shfl_xor(t, 2, 16);
      t += __shfl_xor(t, 4, 16);
      t += __shfl_xor(t, 8, 16);
      float mean = t * (1.0f / 20.0f);
      float c0 = z0 - mean, c1 = z1 - mean;
      float vt = c0 * c0 + ((cl < 4) ? c1 * c1 : 0.f);
      vt += __shfl_xor(vt, 1, 16);
      vt += __shfl_xor(vt, 2, 16);
      vt += __shfl_xor(vt, 4, 16);
      vt += __shfl_xor(vt, 8, 16);
      float rs = rsqrtf(vt * (1.0f / 20.0f) + EPS);
      const long grow = wrbase + rrow;
      if (rrow < 63 && grow < total_rows) {
        Out[grow * 20 + cl] = c0 * rs * gg0 + bb0;
        if (cl < 4) Out[grow * 20 + 16 + cl] = c1 * rs * gg1 + bb1;
      }
    }
  }
}

extern "C" void kernel_launch(void* const* d_in, const int* in_sizes, int n_in,
                              void* d_out, int out_size, void* d_ws, size_t ws_size,
                              hipStream_t stream) {
  const float* X  = (const float*)d_in[0];
  const float* Wq = (const float*)d_in[1];
  const float* bq = (const float*)d_in[2];
  const float* Wk = (const float*)d_in[3];
  const float* bk = (const float*)d_in[4];
  const float* Wv = (const float*)d_in[5];
  const float* bv = (const float*)d_in[6];
  const float* Wo = (const float*)d_in[7];
  const float* bo = (const float*)d_in[8];
  const float* g1 = (const float*)d_in[9];
  const float* b1 = (const float*)d_in[10];
  const float* W1 = (const float*)d_in[11];
  const float* W2 = (const float*)d_in[12];
  const float* g2 = (const float*)d_in[13];
  const float* b2 = (const float*)d_in[14];
  float* Out = (float*)d_out;
  float* ws = (float*)d_ws;

  prep_kernel<<<144, 256, 0, stream>>>(Wq, Wk, Wv, Wo, W1, W2, bq, bk, bv, ws);

  int nblocks = (B_TOT + 27) / 28;  // 4 waves/block * 7 batch elems/wave
  encoder_kernel<<<nblocks, 256, 0, stream>>>(X, ws, bo, g1, b1, g2, b2, Out);
}